// Round 7
// baseline (213.409 us; speedup 1.0000x reference)
//
#include <hip/hip_runtime.h>

typedef unsigned short u16;
typedef unsigned int u32;
typedef unsigned char u8;
typedef _Float16 f16;
typedef __attribute__((ext_vector_type(8))) f16 f16x8;
typedef __attribute__((ext_vector_type(4))) float f32x4;

#define S_LEN 2048
#define DM 1024
#define QKVW 1536
#define KVSTRIDE (S_LEN * 64)   // halfwords per (b,kv) in packed K/V

__device__ __forceinline__ u16 f2h(float x) {
    f16 h = (f16)x;
    return __builtin_bit_cast(u16, h);
}

__device__ __forceinline__ void g2l16(const void* g, void* l) {
    __builtin_amdgcn_global_load_lds((const __attribute__((address_space(1))) u32*)g,
                                     (__attribute__((address_space(3))) u32*)l, 16, 0, 0);
}

// ---------------------------------------------------------------------------
// Fused prep: blocks [0,8192) convert x f32 -> fp16;
// blocks [8192,10752) transpose the 4 weight matrices f32[R=1024][C] -> fp16 [C][1024].
__global__ __launch_bounds__(256)
void prep(const float* __restrict__ x, u16* __restrict__ xh,
          const float* __restrict__ Wq, const float* __restrict__ Wk,
          const float* __restrict__ Wv, const float* __restrict__ Wo,
          u16* __restrict__ Wtq, u16* __restrict__ Wto) {
    __shared__ float tbuf[32][33];
    const int tid = threadIdx.x;
    const int blk = blockIdx.x;
    if (blk < 8192) {
        int i = blk * 256 + tid;
        float4 v = ((const float4*)x)[i];
        ((ushort4*)xh)[i] = make_ushort4(f2h(v.x), f2h(v.y), f2h(v.z), f2h(v.w));
        return;
    }
    int t = blk - 8192;
    const float* src;
    u16* dst;
    int C, cx, ry;
    if (t < 1024)      { src = Wq; dst = Wtq;               C = 1024; cx = t & 31; ry = t >> 5; }
    else if (t < 1280) { t -= 1024; src = Wk; dst = Wtq + 1024 * 1024; C = 256; cx = t & 7; ry = t >> 3; }
    else if (t < 1536) { t -= 1280; src = Wv; dst = Wtq + 1280 * 1024; C = 256; cx = t & 7; ry = t >> 3; }
    else               { t -= 1536; src = Wo; dst = Wto;    C = 1024; cx = t & 31; ry = t >> 5; }
    const int c0 = cx * 32, r0 = ry * 32;
    const int tx = tid & 31, ty = tid >> 5;
#pragma unroll
    for (int i = 0; i < 4; ++i)
        tbuf[ty + 8 * i][tx] = src[(long)(r0 + ty + 8 * i) * C + c0 + tx];
    __syncthreads();
#pragma unroll
    for (int i = 0; i < 4; ++i)
        dst[(long)(c0 + ty + 8 * i) * 1024 + r0 + tx] = f2h(tbuf[tx][ty + 8 * i]);
}

// ---------------------------------------------------------------------------
// m97-style fp16 GEMM, 128x128 tile, global_load_lds(16B), XOR swizzle.
// v8: BK=64 as TWO independent 32-k panels (sA[kh][128][32]); each panel keeps
// the exact proven BK=32 staging/read swizzle. K-steps 32 -> 16: halves the
// number of __syncthreads() vmcnt-drains (the structural ~20% stall).
// FUSED=true (QKV, N=1536): epilogue scatters Q->Qp row-major, K->Kp and
// V->Vp fragment-major. FUSED=false: C = fp32 row-major (out projection).
template <bool FUSED>
__global__ __launch_bounds__(256, 3)
void gemm_bt(const u16* __restrict__ A, const u16* __restrict__ Bt,
             float* __restrict__ Cf, u16* __restrict__ Qp,
             u16* __restrict__ Kp, u16* __restrict__ Vp, int N, int K) {
    __shared__ __attribute__((aligned(16))) u16 sA[2 * 128 * 32];   // [kh][row][32]
    __shared__ __attribute__((aligned(16))) u16 sB[2 * 128 * 32];
    const int tid = threadIdx.x, w = tid >> 6, lane = tid & 63;
    const int quad = lane >> 4, l15 = lane & 15;
    const int wm = w & 1, wn = w >> 1;
    const long row0 = (long)blockIdx.x * 128, col0 = (long)blockIdx.y * 128;

    f32x4 acc[4][4];
#pragma unroll
    for (int mb = 0; mb < 4; ++mb)
#pragma unroll
        for (int nb = 0; nb < 4; ++nb) acc[mb][nb] = (f32x4){0.f, 0.f, 0.f, 0.f};

    const int r = lane >> 2;
    const int cch = (lane & 3) ^ (r & 3);

    for (int kt = 0; kt < K; kt += 64) {
        __syncthreads();
#pragma unroll
        for (int i = 0; i < 8; ++i) {
            int gid = w + 4 * i;            // 0..31
            int buf = gid >> 4, kh = (gid >> 3) & 1, seg = gid & 7;
            const u16* src = buf ? Bt : A;
            long base0 = buf ? col0 : row0;
            const u16* g = src + (base0 + seg * 16 + r) * (long)K + kt + kh * 32 + cch * 8;
            u16* dst = (buf ? sB : sA) + kh * 4096 + seg * 512;
            g2l16(g, dst);
        }
        __syncthreads();

        f16x8 bfr[2][4];
#pragma unroll
        for (int kh = 0; kh < 2; ++kh)
#pragma unroll
            for (int nb = 0; nb < 4; ++nb) {
                int rr = wn * 64 + nb * 16 + l15;
                bfr[kh][nb] = *(const f16x8*)(sB + kh * 4096 + rr * 32 + ((quad ^ (l15 & 3)) * 8));
            }
#pragma unroll
        for (int mb = 0; mb < 4; ++mb) {
            int rr = wm * 64 + mb * 16 + l15;
#pragma unroll
            for (int kh = 0; kh < 2; ++kh) {
                f16x8 af = *(const f16x8*)(sA + kh * 4096 + rr * 32 + ((quad ^ (l15 & 3)) * 8));
#pragma unroll
                for (int nb = 0; nb < 4; ++nb)
                    acc[mb][nb] = __builtin_amdgcn_mfma_f32_16x16x32_f16(af, bfr[kh][nb], acc[mb][nb], 0, 0, 0);
            }
        }
    }

    if constexpr (FUSED) {
        const int bq = (int)(row0 >> 11);          // batch (M = b*2048 + s)
        u16* kpbat = Kp + (long)bq * 4 * KVSTRIDE;
        u16* vpbat = Vp + (long)bq * 4 * KVSTRIDE;
#pragma unroll
        for (int mb = 0; mb < 4; ++mb) {
            const int key0 = ((int)(row0 & 2047)) + wm * 64 + mb * 16 + quad * 4;
#pragma unroll
            for (int nb = 0; nb < 4; ++nb) {
                const int colbase = (int)col0 + wn * 64 + nb * 16;
                if (colbase < 1024) {
#pragma unroll
                    for (int rr = 0; rr < 4; ++rr) {
                        long row = row0 + wm * 64 + mb * 16 + quad * 4 + rr;
                        Qp[row * 1024 + colbase + l15] = f2h(acc[mb][nb][rr]);
                    }
                } else if (colbase < 1280) {
                    const int cc = colbase - 1024;
                    const int d = (cc & 63) + l15;
                    u16* kp = kpbat + (long)(cc >> 6) * KVSTRIDE;
                    const int dpart = (d >> 5) * 512 + ((d >> 3) & 3) * 128 + (d & 7);
#pragma unroll
                    for (int rr = 0; rr < 4; ++rr) {
                        int key = key0 + rr;
                        kp[(key >> 4) * 1024 + (key & 15) * 8 + dpart] = f2h(acc[mb][nb][rr]);
                    }
                } else {
                    const int cc = colbase - 1280;
                    const int d = (cc & 63) + l15;
                    u16* vp = vpbat + (long)(cc >> 6) * KVSTRIDE;
                    const long idx = (long)((key0 >> 5) * 4 + (d >> 4)) * 512 +
                                     ((key0 >> 3) & 3) * 128 + (d & 15) * 8 + (key0 & 7);
                    ushort4 pk = make_ushort4(f2h(acc[mb][nb][0]), f2h(acc[mb][nb][1]),
                                              f2h(acc[mb][nb][2]), f2h(acc[mb][nb][3]));
                    *(ushort4*)(vp + idx) = pk;
                }
            }
        }
    } else {
#pragma unroll
        for (int mb = 0; mb < 4; ++mb)
#pragma unroll
            for (int nb = 0; nb < 4; ++nb)
#pragma unroll
                for (int rr = 0; rr < 4; ++rr) {
                    long row = row0 + wm * 64 + mb * 16 + quad * 4 + rr;
                    long col = col0 + wn * 64 + nb * 16 + l15;
                    Cf[row * N + col] = acc[mb][nb][rr];
                }
    }
}

// ---------------------------------------------------------------------------
// Flash attention, ALiBi static-max, fragment-major K/V, fp16, 32 q-rows/wave.
// v8 = v7 + K-prefetch rotation: kf(kt+1) issued right after QK consumes
// kf(kt); loads stay in flight across the raw s_barrier (no vmcnt drain) so
// K latency hides under softmax+PV instead of stalling the QK phase.
// Softmax denominators via ones-MFMA (lacc), unchanged.
__device__ const u8 UH[21]  = {15,15,14,14,13,13,12,10,12,11,11, 9, 8, 7, 6, 5, 4, 3, 2, 1, 0};
__device__ const u8 UK0[21] = { 0,16, 0,16, 0,16, 1,16,17,10,21,21,24,26,28,29,30,30,31,31,31};
__device__ const u8 UK1[21] = {16,32,16,32,16,32,17,32,32,21,32,32,32,32,32,32,32,32,32,32,32};
__device__ const u8 UC[21]  = { 0, 1, 0, 1, 0, 1, 0, 0, 1, 0, 1, 0, 0, 0, 0, 0, 0, 0, 0, 0, 0};

__global__ __launch_bounds__(256, 4)
void attn(const u16* __restrict__ Qp, const u16* __restrict__ Kp,
          const u16* __restrict__ Vp, u16* __restrict__ Oh,
          float* __restrict__ Of, float* __restrict__ Ls) {
    __shared__ __attribute__((aligned(16))) u16 sP[2][4][16][72];
    const int tid = threadIdx.x, w = tid >> 6, lane = tid & 63;
    const int quad = lane >> 4, l15 = lane & 15;

    const int id = blockIdx.x;
    const int u = id >> 6, s = id & 63;
    const int b = s >> 4, qt = s & 15;
    const int h = UH[u];
    const int kt0 = UK0[u], kt1 = UK1[u];
    const int chunk = UC[u];
    const bool split = (u <= 10) && (u != 7);
    const int kvh = h >> 2;

    const float c1 = 0.125f * 1.44269504f;
    const float c2 = __builtin_amdgcn_exp2f(-0.5f * (float)(h + 1)) * 1.44269504f;
    const float d0 = -8.0f - c2 * 2047.0f;

    const long qrow0 = (long)b * S_LEN + qt * 128 + w * 32;

    f16x8 qf[2][2];
#pragma unroll
    for (int rg = 0; rg < 2; ++rg)
#pragma unroll
        for (int ch = 0; ch < 2; ++ch)
            qf[rg][ch] = *(const f16x8*)(Qp + (qrow0 + rg * 16 + l15) * 1024 +
                                         h * 64 + ch * 32 + quad * 8);

    const f16x8 vone = {(f16)1.f, (f16)1.f, (f16)1.f, (f16)1.f,
                        (f16)1.f, (f16)1.f, (f16)1.f, (f16)1.f};

    f32x4 oacc[2][4];
    f32x4 lacc[2];                       // row-sums via ones-MFMA
#pragma unroll
    for (int rg = 0; rg < 2; ++rg) {
#pragma unroll
        for (int nb = 0; nb < 4; ++nb) oacc[rg][nb] = (f32x4){0.f, 0.f, 0.f, 0.f};
        lacc[rg] = (f32x4){0.f, 0.f, 0.f, 0.f};
    }

    const u16* kpb = Kp + (long)(b * 4 + kvh) * KVSTRIDE + lane * 8;
    const u16* vpb = Vp + (long)(b * 4 + kvh) * KVSTRIDE + lane * 8;

    // prologue: preload K(kt0)
    f16x8 kf[8];
#pragma unroll
    for (int j = 0; j < 8; ++j)
        kf[j] = *(const f16x8*)(kpb + (long)(kt0 * 8 + j) * 512);

    for (int kt = kt0; kt < kt1; ++kt) {
        __builtin_amdgcn_s_barrier();       // lockstep for L1 reuse (no data dep)

        // QK^T consuming kf
        f32x4 z[2][4];
        __builtin_amdgcn_s_setprio(1);
#pragma unroll
        for (int rg = 0; rg < 2; ++rg)
#pragma unroll
            for (int kb = 0; kb < 4; ++kb) {
                f32x4 zz = (f32x4){0.f, 0.f, 0.f, 0.f};
                zz = __builtin_amdgcn_mfma_f32_16x16x32_f16(qf[rg][0], kf[2 * kb], zz, 0, 0, 0);
                zz = __builtin_amdgcn_mfma_f32_16x16x32_f16(qf[rg][1], kf[2 * kb + 1], zz, 0, 0, 0);
                z[rg][kb] = zz;
            }
        __builtin_amdgcn_s_setprio(0);

        // prefetch next K (branchless clamp; latency hidden under softmax+PV)
        const int ktn = (kt + 1 < kt1) ? kt + 1 : kt;
#pragma unroll
        for (int j = 0; j < 8; ++j)
            kf[j] = *(const f16x8*)(kpb + (long)(ktn * 8 + j) * 512);

        // softmax numerator
        const float kcb = fmaf(c2, (float)(kt * 64 + l15), d0);
#pragma unroll
        for (int rg = 0; rg < 2; ++rg)
#pragma unroll
            for (int kb = 0; kb < 4; ++kb) {
                float kc = fmaf(c2, (float)(16 * kb), kcb);
#pragma unroll
                for (int rr = 0; rr < 4; ++rr) {
                    float p = __builtin_amdgcn_exp2f(fmaf(z[rg][kb][rr], c1, kc));
                    sP[rg][w][quad * 4 + rr][kb * 16 + l15] = f2h(p);
                }
            }

        // V loads + PV
        f16x8 vf[8];
#pragma unroll
        for (int j = 0; j < 8; ++j)
            vf[j] = *(const f16x8*)(vpb + (long)(kt * 8 + j) * 512);
#pragma unroll
        for (int rg = 0; rg < 2; ++rg)
#pragma unroll
            for (int ch = 0; ch < 2; ++ch) {
                f16x8 pf = *(const f16x8*)(&sP[rg][w][l15][ch * 32 + quad * 8]);
                __builtin_amdgcn_s_setprio(1);
#pragma unroll
                for (int nb = 0; nb < 4; ++nb)
                    oacc[rg][nb] = __builtin_amdgcn_mfma_f32_16x16x32_f16(pf, vf[ch * 4 + nb],
                                                                          oacc[rg][nb], 0, 0, 0);
                lacc[rg] = __builtin_amdgcn_mfma_f32_16x16x32_f16(pf, vone, lacc[rg], 0, 0, 0);
                __builtin_amdgcn_s_setprio(0);
            }
    }

#pragma unroll
    for (int rg = 0; rg < 2; ++rg) {
        if (split) {
            const int hs = h - 11;
#pragma unroll
            for (int rr = 0; rr < 4; ++rr) {
                long rowg = qrow0 + rg * 16 + quad * 4 + rr;
                if (l15 == 0)
                    Ls[(long)(chunk * 8192) * 5 + rowg * 5 + hs] = lacc[rg][rr];
#pragma unroll
                for (int nb = 0; nb < 4; ++nb)
                    Of[((long)(chunk * 8192) + rowg) * 320 + hs * 64 + nb * 16 + l15] =
                        oacc[rg][nb][rr];
            }
        } else {
#pragma unroll
            for (int rr = 0; rr < 4; ++rr) {
                const float linv = 1.0f / lacc[rg][rr];
#pragma unroll
                for (int nb = 0; nb < 4; ++nb) {
                    long row = qrow0 + rg * 16 + quad * 4 + rr;
                    long col = h * 64 + nb * 16 + l15;
                    Oh[row * DM + col] = f2h(oacc[rg][nb][rr] * linv);
                }
            }
        }
    }
}

// ---------------------------------------------------------------------------
// Combine the 2 chunk partials for split heads (h 11..15), normalize, write Oh.
// Of: [2][8192][5][64] fp32, Ls: [2][8192][5] fp32 (both in d_out scratch).
__global__ __launch_bounds__(256)
void norm_split(const float* __restrict__ Of, const float* __restrict__ Ls,
                u16* __restrict__ Oh) {
    const int gid = blockIdx.x * 256 + threadIdx.x;   // 655360 total
    const int d4 = gid & 15;
    const int rh = gid >> 4;                          // row*5 + hs, 40960 total
    const int hs = rh % 5;
    const int row = rh / 5;
    const float l = Ls[rh] + Ls[rh + 40960];
    const float4 a = ((const float4*)Of)[rh * 16 + d4];
    const float4 bq = ((const float4*)Of)[(rh + 40960) * 16 + d4];
    const float inv = 1.0f / l;
    const int col = (hs + 11) * 64 + d4 * 4;
    ((ushort4*)(Oh + (long)row * DM + col))[0] =
        make_ushort4(f2h((a.x + bq.x) * inv), f2h((a.y + bq.y) * inv),
                     f2h((a.z + bq.z) * inv), f2h((a.w + bq.w) * inv));
}

// ---------------------------------------------------------------------------
extern "C" void kernel_launch(void* const* d_in, const int* in_sizes, int n_in,
                              void* d_out, int out_size, void* d_ws, size_t ws_size,
                              hipStream_t stream) {
    const float* x = (const float*)d_in[0];
    const float* Wq = (const float*)d_in[1];
    const float* Wk = (const float*)d_in[2];
    const float* Wv = (const float*)d_in[3];
    const float* Wo = (const float*)d_in[4];
    char* ws = (char*)d_ws;
    const size_t MB = 1 << 20;

    // ws: xh 16MB | Wtq 3MB | Wto 2MB | Qp 16MB | Kp 4MB | Vp 4MB  (45MB)
    u16* xh = (u16*)ws;
    u16* Wtq = (u16*)(ws + 16 * MB);
    u16* Wto = (u16*)(ws + 19 * MB);
    u16* Qp = (u16*)(ws + 21 * MB);
    u16* Kp = (u16*)(ws + 37 * MB);
    u16* Vp = (u16*)(ws + 41 * MB);
    u16* Oh = xh;                       // x dead after QKV GEMM

    // d_out (33.5MB fp32) doubles as split-head partial scratch before the
    // out-projection GEMM overwrites it: Of 2*8192*5*64 f32 (21MB) + Ls.
    float* Of = (float*)d_out;
    float* Ls = Of + 2 * 8192 * 5 * 64;

    prep<<<10752, 256, 0, stream>>>(x, xh, Wq, Wk, Wv, Wo, Wtq, Wto);
    gemm_bt<true><<<dim3(64, 12), 256, 0, stream>>>(xh, Wtq, nullptr, Qp, Kp, Vp, QKVW, 1024);
    attn<<<1344, 256, 0, stream>>>(Qp, Kp, Vp, Oh, Of, Ls);
    norm_split<<<2560, 256, 0, stream>>>(Of, Ls, Oh);
    gemm_bt<false><<<dim3(64, 8), 256, 0, stream>>>(Oh, Wto, (float*)d_out, nullptr, nullptr, nullptr, 1024, 1024);
}

// Round 8
// 193.745 us; speedup vs baseline: 1.1015x; 1.1015x over previous
//
#include <hip/hip_runtime.h>

typedef unsigned short u16;
typedef unsigned int u32;
typedef unsigned char u8;
typedef _Float16 f16;
typedef __attribute__((ext_vector_type(8))) f16 f16x8;
typedef __attribute__((ext_vector_type(4))) float f32x4;

#define S_LEN 2048
#define DM 1024
#define QKVW 1536
#define KVSTRIDE (S_LEN * 64)   // halfwords per (b,kv) in packed K/V

__device__ __forceinline__ u16 f2h(float x) {
    f16 h = (f16)x;
    return __builtin_bit_cast(u16, h);
}

__device__ __forceinline__ void g2l16(const void* g, void* l) {
    __builtin_amdgcn_global_load_lds((const __attribute__((address_space(1))) u32*)g,
                                     (__attribute__((address_space(3))) u32*)l, 16, 0, 0);
}

// ---------------------------------------------------------------------------
// Fused prep: blocks [0,8192) convert x f32 -> fp16;
// blocks [8192,10752) transpose the 4 weight matrices f32[R=1024][C] -> fp16 [C][1024].
__global__ __launch_bounds__(256)
void prep(const float* __restrict__ x, u16* __restrict__ xh,
          const float* __restrict__ Wq, const float* __restrict__ Wk,
          const float* __restrict__ Wv, const float* __restrict__ Wo,
          u16* __restrict__ Wtq, u16* __restrict__ Wto) {
    __shared__ float tbuf[32][33];
    const int tid = threadIdx.x;
    const int blk = blockIdx.x;
    if (blk < 8192) {
        int i = blk * 256 + tid;
        float4 v = ((const float4*)x)[i];
        ((ushort4*)xh)[i] = make_ushort4(f2h(v.x), f2h(v.y), f2h(v.z), f2h(v.w));
        return;
    }
    int t = blk - 8192;
    const float* src;
    u16* dst;
    int C, cx, ry;
    if (t < 1024)      { src = Wq; dst = Wtq;               C = 1024; cx = t & 31; ry = t >> 5; }
    else if (t < 1280) { t -= 1024; src = Wk; dst = Wtq + 1024 * 1024; C = 256; cx = t & 7; ry = t >> 3; }
    else if (t < 1536) { t -= 1280; src = Wv; dst = Wtq + 1280 * 1024; C = 256; cx = t & 7; ry = t >> 3; }
    else               { t -= 1536; src = Wo; dst = Wto;    C = 1024; cx = t & 31; ry = t >> 5; }
    const int c0 = cx * 32, r0 = ry * 32;
    const int tx = tid & 31, ty = tid >> 5;
#pragma unroll
    for (int i = 0; i < 4; ++i)
        tbuf[ty + 8 * i][tx] = src[(long)(r0 + ty + 8 * i) * C + c0 + tx];
    __syncthreads();
#pragma unroll
    for (int i = 0; i < 4; ++i)
        dst[(long)(c0 + ty + 8 * i) * 1024 + r0 + tx] = f2h(tbuf[tx][ty + 8 * i]);
}

// ---------------------------------------------------------------------------
// m97-style fp16 GEMM, 128x128 tile, global_load_lds(16B), XOR swizzle.
// v8 (KEPT from r7 -- proven ~11.5us combined win): BK=64 as TWO independent
// 32-k panels (sA[kh][128][32]); each panel keeps the exact proven BK=32
// staging/read swizzle. K-steps 32 -> 16: halves the __syncthreads()
// vmcnt-drain count (the structural ~20% stall).
// FUSED=true (QKV, N=1536): epilogue scatters Q->Qp row-major, K->Kp and
// V->Vp fragment-major. FUSED=false: C = fp32 row-major (out projection).
template <bool FUSED>
__global__ __launch_bounds__(256, 3)
void gemm_bt(const u16* __restrict__ A, const u16* __restrict__ Bt,
             float* __restrict__ Cf, u16* __restrict__ Qp,
             u16* __restrict__ Kp, u16* __restrict__ Vp, int N, int K) {
    __shared__ __attribute__((aligned(16))) u16 sA[2 * 128 * 32];   // [kh][row][32]
    __shared__ __attribute__((aligned(16))) u16 sB[2 * 128 * 32];
    const int tid = threadIdx.x, w = tid >> 6, lane = tid & 63;
    const int quad = lane >> 4, l15 = lane & 15;
    const int wm = w & 1, wn = w >> 1;
    const long row0 = (long)blockIdx.x * 128, col0 = (long)blockIdx.y * 128;

    f32x4 acc[4][4];
#pragma unroll
    for (int mb = 0; mb < 4; ++mb)
#pragma unroll
        for (int nb = 0; nb < 4; ++nb) acc[mb][nb] = (f32x4){0.f, 0.f, 0.f, 0.f};

    const int r = lane >> 2;
    const int cch = (lane & 3) ^ (r & 3);

    for (int kt = 0; kt < K; kt += 64) {
        __syncthreads();
#pragma unroll
        for (int i = 0; i < 8; ++i) {
            int gid = w + 4 * i;            // 0..31
            int buf = gid >> 4, kh = (gid >> 3) & 1, seg = gid & 7;
            const u16* src = buf ? Bt : A;
            long base0 = buf ? col0 : row0;
            const u16* g = src + (base0 + seg * 16 + r) * (long)K + kt + kh * 32 + cch * 8;
            u16* dst = (buf ? sB : sA) + kh * 4096 + seg * 512;
            g2l16(g, dst);
        }
        __syncthreads();

        f16x8 bfr[2][4];
#pragma unroll
        for (int kh = 0; kh < 2; ++kh)
#pragma unroll
            for (int nb = 0; nb < 4; ++nb) {
                int rr = wn * 64 + nb * 16 + l15;
                bfr[kh][nb] = *(const f16x8*)(sB + kh * 4096 + rr * 32 + ((quad ^ (l15 & 3)) * 8));
            }
#pragma unroll
        for (int mb = 0; mb < 4; ++mb) {
            int rr = wm * 64 + mb * 16 + l15;
#pragma unroll
            for (int kh = 0; kh < 2; ++kh) {
                f16x8 af = *(const f16x8*)(sA + kh * 4096 + rr * 32 + ((quad ^ (l15 & 3)) * 8));
#pragma unroll
                for (int nb = 0; nb < 4; ++nb)
                    acc[mb][nb] = __builtin_amdgcn_mfma_f32_16x16x32_f16(af, bfr[kh][nb], acc[mb][nb], 0, 0, 0);
            }
        }
    }

    if constexpr (FUSED) {
        const int bq = (int)(row0 >> 11);          // batch (M = b*2048 + s)
        u16* kpbat = Kp + (long)bq * 4 * KVSTRIDE;
        u16* vpbat = Vp + (long)bq * 4 * KVSTRIDE;
#pragma unroll
        for (int mb = 0; mb < 4; ++mb) {
            const int key0 = ((int)(row0 & 2047)) + wm * 64 + mb * 16 + quad * 4;
#pragma unroll
            for (int nb = 0; nb < 4; ++nb) {
                const int colbase = (int)col0 + wn * 64 + nb * 16;
                if (colbase < 1024) {
#pragma unroll
                    for (int rr = 0; rr < 4; ++rr) {
                        long row = row0 + wm * 64 + mb * 16 + quad * 4 + rr;
                        Qp[row * 1024 + colbase + l15] = f2h(acc[mb][nb][rr]);
                    }
                } else if (colbase < 1280) {
                    const int cc = colbase - 1024;
                    const int d = (cc & 63) + l15;
                    u16* kp = kpbat + (long)(cc >> 6) * KVSTRIDE;
                    const int dpart = (d >> 5) * 512 + ((d >> 3) & 3) * 128 + (d & 7);
#pragma unroll
                    for (int rr = 0; rr < 4; ++rr) {
                        int key = key0 + rr;
                        kp[(key >> 4) * 1024 + (key & 15) * 8 + dpart] = f2h(acc[mb][nb][rr]);
                    }
                } else {
                    const int cc = colbase - 1280;
                    const int d = (cc & 63) + l15;
                    u16* vp = vpbat + (long)(cc >> 6) * KVSTRIDE;
                    const long idx = (long)((key0 >> 5) * 4 + (d >> 4)) * 512 +
                                     ((key0 >> 3) & 3) * 128 + (d & 15) * 8 + (key0 & 7);
                    ushort4 pk = make_ushort4(f2h(acc[mb][nb][0]), f2h(acc[mb][nb][1]),
                                              f2h(acc[mb][nb][2]), f2h(acc[mb][nb][3]));
                    *(ushort4*)(vp + idx) = pk;
                }
            }
        }
    } else {
#pragma unroll
        for (int mb = 0; mb < 4; ++mb)
#pragma unroll
            for (int nb = 0; nb < 4; ++nb)
#pragma unroll
                for (int rr = 0; rr < 4; ++rr) {
                    long row = row0 + wm * 64 + mb * 16 + quad * 4 + rr;
                    long col = col0 + wn * 64 + nb * 16 + l15;
                    Cf[row * N + col] = acc[mb][nb][rr];
                }
    }
}

// ---------------------------------------------------------------------------
// Flash attention, ALiBi static-max, fragment-major K/V, fp16, 32 q-rows/wave.
// v9 = EXACT r6 body (known-good 47.4us): per-wave K/V reg loads, single raw
// s_barrier, ones-MFMA row-sums. K-prefetch REVERTED (r7: spilled ~42MB
// scratch, +25us -- third failed pipelining attempt; implicit TLP at
// 4-5 blocks/CU is the best latency hiding for this structure).
__device__ const u8 UH[21]  = {15,15,14,14,13,13,12,10,12,11,11, 9, 8, 7, 6, 5, 4, 3, 2, 1, 0};
__device__ const u8 UK0[21] = { 0,16, 0,16, 0,16, 1,16,17,10,21,21,24,26,28,29,30,30,31,31,31};
__device__ const u8 UK1[21] = {16,32,16,32,16,32,17,32,32,21,32,32,32,32,32,32,32,32,32,32,32};
__device__ const u8 UC[21]  = { 0, 1, 0, 1, 0, 1, 0, 0, 1, 0, 1, 0, 0, 0, 0, 0, 0, 0, 0, 0, 0};

__global__ __launch_bounds__(256, 4)
void attn(const u16* __restrict__ Qp, const u16* __restrict__ Kp,
          const u16* __restrict__ Vp, u16* __restrict__ Oh,
          float* __restrict__ Of, float* __restrict__ Ls) {
    __shared__ __attribute__((aligned(16))) u16 sP[2][4][16][72];
    const int tid = threadIdx.x, w = tid >> 6, lane = tid & 63;
    const int quad = lane >> 4, l15 = lane & 15;

    const int id = blockIdx.x;
    const int u = id >> 6, s = id & 63;
    const int b = s >> 4, qt = s & 15;
    const int h = UH[u];
    const int kt0 = UK0[u], kt1 = UK1[u];
    const int chunk = UC[u];
    const bool split = (u <= 10) && (u != 7);
    const int kvh = h >> 2;

    const float c1 = 0.125f * 1.44269504f;
    const float c2 = __builtin_amdgcn_exp2f(-0.5f * (float)(h + 1)) * 1.44269504f;
    const float d0 = -8.0f - c2 * 2047.0f;

    const long qrow0 = (long)b * S_LEN + qt * 128 + w * 32;

    f16x8 qf[2][2];
#pragma unroll
    for (int rg = 0; rg < 2; ++rg)
#pragma unroll
        for (int ch = 0; ch < 2; ++ch)
            qf[rg][ch] = *(const f16x8*)(Qp + (qrow0 + rg * 16 + l15) * 1024 +
                                         h * 64 + ch * 32 + quad * 8);

    const f16x8 vone = {(f16)1.f, (f16)1.f, (f16)1.f, (f16)1.f,
                        (f16)1.f, (f16)1.f, (f16)1.f, (f16)1.f};

    f32x4 oacc[2][4];
    f32x4 lacc[2];                       // row-sums via ones-MFMA
#pragma unroll
    for (int rg = 0; rg < 2; ++rg) {
#pragma unroll
        for (int nb = 0; nb < 4; ++nb) oacc[rg][nb] = (f32x4){0.f, 0.f, 0.f, 0.f};
        lacc[rg] = (f32x4){0.f, 0.f, 0.f, 0.f};
    }

    const u16* kpb = Kp + (long)(b * 4 + kvh) * KVSTRIDE + lane * 8;
    const u16* vpb = Vp + (long)(b * 4 + kvh) * KVSTRIDE + lane * 8;

    for (int kt = kt0; kt < kt1; ++kt) {
        __builtin_amdgcn_s_barrier();       // lockstep for L1 reuse (no data dep)
        f16x8 kf[8];
#pragma unroll
        for (int j = 0; j < 8; ++j)
            kf[j] = *(const f16x8*)(kpb + (long)(kt * 8 + j) * 512);
        const float kcb = fmaf(c2, (float)(kt * 64 + l15), d0);
#pragma unroll
        for (int rg = 0; rg < 2; ++rg) {
#pragma unroll
            for (int kb = 0; kb < 4; ++kb) {
                f32x4 z = (f32x4){0.f, 0.f, 0.f, 0.f};
                __builtin_amdgcn_s_setprio(1);
                z = __builtin_amdgcn_mfma_f32_16x16x32_f16(qf[rg][0], kf[2 * kb], z, 0, 0, 0);
                z = __builtin_amdgcn_mfma_f32_16x16x32_f16(qf[rg][1], kf[2 * kb + 1], z, 0, 0, 0);
                __builtin_amdgcn_s_setprio(0);
                float kc = fmaf(c2, (float)(16 * kb), kcb);
#pragma unroll
                for (int rr = 0; rr < 4; ++rr) {
                    float p = __builtin_amdgcn_exp2f(fmaf(z[rr], c1, kc));
                    sP[rg][w][quad * 4 + rr][kb * 16 + l15] = f2h(p);
                }
            }
        }
        f16x8 vf[8];
#pragma unroll
        for (int j = 0; j < 8; ++j)
            vf[j] = *(const f16x8*)(vpb + (long)(kt * 8 + j) * 512);
#pragma unroll
        for (int rg = 0; rg < 2; ++rg)
#pragma unroll
            for (int ch = 0; ch < 2; ++ch) {
                f16x8 pf = *(const f16x8*)(&sP[rg][w][l15][ch * 32 + quad * 8]);
                __builtin_amdgcn_s_setprio(1);
#pragma unroll
                for (int nb = 0; nb < 4; ++nb)
                    oacc[rg][nb] = __builtin_amdgcn_mfma_f32_16x16x32_f16(pf, vf[ch * 4 + nb],
                                                                          oacc[rg][nb], 0, 0, 0);
                lacc[rg] = __builtin_amdgcn_mfma_f32_16x16x32_f16(pf, vone, lacc[rg], 0, 0, 0);
                __builtin_amdgcn_s_setprio(0);
            }
    }

#pragma unroll
    for (int rg = 0; rg < 2; ++rg) {
        if (split) {
            const int hs = h - 11;
#pragma unroll
            for (int rr = 0; rr < 4; ++rr) {
                long rowg = qrow0 + rg * 16 + quad * 4 + rr;
                if (l15 == 0)
                    Ls[(long)(chunk * 8192) * 5 + rowg * 5 + hs] = lacc[rg][rr];
#pragma unroll
                for (int nb = 0; nb < 4; ++nb)
                    Of[((long)(chunk * 8192) + rowg) * 320 + hs * 64 + nb * 16 + l15] =
                        oacc[rg][nb][rr];
            }
        } else {
#pragma unroll
            for (int rr = 0; rr < 4; ++rr) {
                const float linv = 1.0f / lacc[rg][rr];
#pragma unroll
                for (int nb = 0; nb < 4; ++nb) {
                    long row = qrow0 + rg * 16 + quad * 4 + rr;
                    long col = h * 64 + nb * 16 + l15;
                    Oh[row * DM + col] = f2h(oacc[rg][nb][rr] * linv);
                }
            }
        }
    }
}

// ---------------------------------------------------------------------------
// Combine the 2 chunk partials for split heads (h 11..15), normalize, write Oh.
// Of: [2][8192][5][64] fp32, Ls: [2][8192][5] fp32 (both in d_out scratch).
__global__ __launch_bounds__(256)
void norm_split(const float* __restrict__ Of, const float* __restrict__ Ls,
                u16* __restrict__ Oh) {
    const int gid = blockIdx.x * 256 + threadIdx.x;   // 655360 total
    const int d4 = gid & 15;
    const int rh = gid >> 4;                          // row*5 + hs, 40960 total
    const int hs = rh % 5;
    const int row = rh / 5;
    const float l = Ls[rh] + Ls[rh + 40960];
    const float4 a = ((const float4*)Of)[rh * 16 + d4];
    const float4 bq = ((const float4*)Of)[(rh + 40960) * 16 + d4];
    const float inv = 1.0f / l;
    const int col = (hs + 11) * 64 + d4 * 4;
    ((ushort4*)(Oh + (long)row * DM + col))[0] =
        make_ushort4(f2h((a.x + bq.x) * inv), f2h((a.y + bq.y) * inv),
                     f2h((a.z + bq.z) * inv), f2h((a.w + bq.w) * inv));
}

// ---------------------------------------------------------------------------
extern "C" void kernel_launch(void* const* d_in, const int* in_sizes, int n_in,
                              void* d_out, int out_size, void* d_ws, size_t ws_size,
                              hipStream_t stream) {
    const float* x = (const float*)d_in[0];
    const float* Wq = (const float*)d_in[1];
    const float* Wk = (const float*)d_in[2];
    const float* Wv = (const float*)d_in[3];
    const float* Wo = (const float*)d_in[4];
    char* ws = (char*)d_ws;
    const size_t MB = 1 << 20;

    // ws: xh 16MB | Wtq 3MB | Wto 2MB | Qp 16MB | Kp 4MB | Vp 4MB  (45MB)
    u16* xh = (u16*)ws;
    u16* Wtq = (u16*)(ws + 16 * MB);
    u16* Wto = (u16*)(ws + 19 * MB);
    u16* Qp = (u16*)(ws + 21 * MB);
    u16* Kp = (u16*)(ws + 37 * MB);
    u16* Vp = (u16*)(ws + 41 * MB);
    u16* Oh = xh;                       // x dead after QKV GEMM

    // d_out (33.5MB fp32) doubles as split-head partial scratch before the
    // out-projection GEMM overwrites it: Of 2*8192*5*64 f32 (21MB) + Ls.
    float* Of = (float*)d_out;
    float* Ls = Of + 2 * 8192 * 5 * 64;

    prep<<<10752, 256, 0, stream>>>(x, xh, Wq, Wk, Wv, Wo, Wtq, Wto);
    gemm_bt<true><<<dim3(64, 12), 256, 0, stream>>>(xh, Wtq, nullptr, Qp, Kp, Vp, QKVW, 1024);
    attn<<<1344, 256, 0, stream>>>(Qp, Kp, Vp, Oh, Of, Ls);
    norm_split<<<2560, 256, 0, stream>>>(Of, Ls, Oh);
    gemm_bt<false><<<dim3(64, 8), 256, 0, stream>>>(Oh, Wto, (float*)d_out, nullptr, nullptr, nullptr, 1024, 1024);
}